// Round 14
// baseline (3752.795 us; speedup 1.0000x reference)
//
#include <hip/hip_runtime.h>

// ---------- types ----------
typedef short short8 __attribute__((ext_vector_type(8)));   // 8 bf16 as i16
typedef float f32x4 __attribute__((ext_vector_type(4)));

#define GLOBAL_AS __attribute__((address_space(1)))
#define LDS_AS    __attribute__((address_space(3)))

__device__ __forceinline__ unsigned short f2bf(float f) {
    unsigned u = __builtin_bit_cast(unsigned, f);
    u += 0x7fffu + ((u >> 16) & 1u);          // round-to-nearest-even
    return (unsigned short)(u >> 16);
}

// ---------- convert kernels (memory-bound, vectorized) ----------
__global__ __launch_bounds__(256) void k_idx2bf(const int* __restrict__ idx,
                                                const float* __restrict__ cb,
                                                ushort* __restrict__ out, int n4) {
    int i = blockIdx.x * 256 + threadIdx.x;
    if (i >= n4) return;
    int4 v = reinterpret_cast<const int4*>(idx)[i];
    ushort4 o;
    o.x = f2bf(cb[v.x]); o.y = f2bf(cb[v.y]);
    o.z = f2bf(cb[v.z]); o.w = f2bf(cb[v.w]);
    reinterpret_cast<ushort4*>(out)[i] = o;
}

__global__ __launch_bounds__(256) void k_f2bf(const float* __restrict__ in,
                                              ushort* __restrict__ out, int n4) {
    int i = blockIdx.x * 256 + threadIdx.x;
    if (i >= n4) return;
    float4 v = reinterpret_cast<const float4*>(in)[i];
    ushort4 o;
    o.x = f2bf(v.x); o.y = f2bf(v.y); o.z = f2bf(v.z); o.w = f2bf(v.w);
    reinterpret_cast<ushort4*>(out)[i] = o;
}

// ===== shared geometry macros (both GEMM kernels) =====
// chunk maps: chunk = 8 rows = 1024B staged linearly; A-early/late, B-early/late
#define CH_AE(j) ((((j) & 8) << 1) | ((j) & 7))
#define CH_AL(j) (CH_AE(j) + 8)
#define CH_BE(j) ((((j) & 12) << 1) | ((j) & 3))
#define CH_BL(j) (CH_BE(j) + 4)

#define STAGE2(GB, LW, KB, CF) do {                                             \
    const int c0_ = CF(2 * w);                                                  \
    const int c1_ = CF(2 * w + 1);                                              \
    __builtin_amdgcn_global_load_lds(                                           \
        (const GLOBAL_AS void*)((GB) + (size_t)c0_ * 32768 + (KB)),             \
        (LDS_AS void*)((LW) + c0_ * 512), 16, 0, 0);                            \
    __builtin_amdgcn_global_load_lds(                                           \
        (const GLOBAL_AS void*)((GB) + (size_t)c1_ * 32768 + (KB)),             \
        (LDS_AS void*)((LW) + c1_ * 512), 16, 0, 0);                            \
} while (0)

// static-offset fragment reads: BUFOFF/MH/NH are literal tokens -> ds imm
#define READ_A(DST, BUFOFF, MH) do {                                            \
    _Pragma("unroll")                                                           \
    for (int mi = 0; mi < 4; ++mi)                                              \
        DST[0][mi] = *reinterpret_cast<const short8*>(                          \
            sAc + ak0 + ((BUFOFF) + (MH) * 8192 + mi * 2048));                  \
    _Pragma("unroll")                                                           \
    for (int mi = 0; mi < 4; ++mi)                                              \
        DST[1][mi] = *reinterpret_cast<const short8*>(                          \
            sAc + ak1 + ((BUFOFF) + (MH) * 8192 + mi * 2048));                  \
} while (0)

#define READ_B(DST, BUFOFF, NH) do {                                            \
    _Pragma("unroll")                                                           \
    for (int ni = 0; ni < 2; ++ni)                                              \
        DST[0][ni] = *reinterpret_cast<const short8*>(                          \
            sBc + bk0 + ((BUFOFF) + (NH) * 4096 + ni * 2048));                  \
    _Pragma("unroll")                                                           \
    for (int ni = 0; ni < 2; ++ni)                                              \
        DST[1][ni] = *reinterpret_cast<const short8*>(                          \
            sBc + bk1 + ((BUFOFF) + (NH) * 4096 + ni * 2048));                  \
} while (0)

#define MFMA16Q(MH, NH, AF, BF)                                                 \
    _Pragma("unroll")                                                           \
    for (int k2 = 0; k2 < 2; ++k2)                                              \
        _Pragma("unroll")                                                       \
        for (int mi = 0; mi < 4; ++mi)                                          \
            _Pragma("unroll")                                                   \
            for (int ni = 0; ni < 2; ++ni)                                      \
                acc[(MH) * 4 + mi][(NH) * 2 + ni] =                             \
                    __builtin_amdgcn_mfma_f32_16x16x32_bf16(                    \
                        AF[k2][mi], BF[k2][ni], acc[(MH) * 4 + mi][(NH) * 2 + ni], 0, 0, 0)

#define BARX do {                                                               \
    asm volatile("" ::: "memory");                                              \
    __builtin_amdgcn_s_barrier();                                               \
    asm volatile("" ::: "memory");                                              \
} while (0)

#define GEOM_COMMON(AP, BP)                                                     \
    constexpr int K = 4096, N = 4096;                                           \
    const int tid  = threadIdx.x;                                               \
    const int w    = tid >> 6;                                                  \
    const int lane = tid & 63;                                                  \
    const int wm = w >> 2, wn = w & 3;                                          \
    const int nwg = gridDim.x;                                                  \
    const int sw  = ((int)blockIdx.x & 7) * (nwg >> 3) + ((int)blockIdx.x >> 3);\
    const int m0 = (sw >> 4) * 256;                                             \
    const int n0 = (sw & 15) * 256;                                             \
    const int srow8 = lane >> 3;                                                \
    const int scol  = (((lane & 7) ^ (lane >> 3)) * 8);                         \
    const ushort* gAl = (AP) + (size_t)m0 * K + srow8 * 4096 + scol;            \
    const ushort* gBl = (BP) + (size_t)n0 * K + srow8 * 4096 + scol;            \
    const int fr   = lane & 15;                                                 \
    const int fkb  = ((lane >> 4) & 3) * 16;                                    \
    const int swb  = (fr & 7) << 4;                                             \
    const int arow = wm * 128 + fr;                                             \
    const int brow = wn * 64 + fr;                                              \
    const int ak0 = (arow * 128 + 0  + fkb) ^ swb;                              \
    const int ak1 = (arow * 128 + 64 + fkb) ^ swb;                              \
    const int bk0 = (brow * 128 + 0  + fkb) ^ swb;                              \
    const int bk1 = (brow * 128 + 64 + fkb) ^ swb

#define EPILOGUE_COMMON                                                         \
    const int rb = m0 + wm * 128 + ((lane >> 4) * 4);                           \
    const int cb = n0 + wn * 64 + (lane & 15);                                  \
    if (EPI == 0) {                                                             \
        ushort* Cw = (ushort*)C;                                                \
        _Pragma("unroll")                                                       \
        for (int mi = 0; mi < 8; ++mi)                                          \
            _Pragma("unroll")                                                   \
            for (int r = 0; r < 4; ++r) {                                       \
                const int row = rb + mi * 16 + r;                               \
                const float s = extra[row];                                     \
                _Pragma("unroll")                                               \
                for (int ni = 0; ni < 4; ++ni)                                  \
                    Cw[(size_t)row * N + cb + ni * 16] = f2bf(acc[mi][ni][r] * s); \
            }                                                                   \
    } else {                                                                    \
        float* Cf = (float*)C;                                                  \
        _Pragma("unroll")                                                       \
        for (int ni = 0; ni < 4; ++ni) {                                        \
            const float b = extra[cb + ni * 16];                                \
            _Pragma("unroll")                                                   \
            for (int mi = 0; mi < 8; ++mi)                                      \
                _Pragma("unroll")                                               \
                for (int r = 0; r < 4; ++r) {                                   \
                    const int row = rb + mi * 16 + r;                           \
                    Cf[(size_t)row * N + cb + ni * 16] = acc[mi][ni][r] + b;    \
                }                                                               \
        }                                                                       \
    }

// ---------- kernel 1: round-10 double-buffered 4-phase (for 1 block/CU) ----
#define PH_MID do {                                                             \
    asm volatile("" ::: "memory");                                              \
    __builtin_amdgcn_s_barrier();                                               \
    asm volatile("s_waitcnt lgkmcnt(0)" ::: "memory");                          \
    __builtin_amdgcn_sched_barrier(0);                                          \
    __builtin_amdgcn_s_setprio(1);                                              \
} while (0)

#define PH_END do {                                                             \
    __builtin_amdgcn_s_setprio(0);                                              \
    asm volatile("" ::: "memory");                                              \
    __builtin_amdgcn_s_barrier();                                               \
    asm volatile("" ::: "memory");                                              \
} while (0)

#define PH1S(BUFOFF, ...) do {                                                  \
    READ_A(aF, BUFOFF, 0); READ_B(b0f, BUFOFF, 0);                              \
    __VA_ARGS__;                                                                \
    asm volatile("s_waitcnt lgkmcnt(8)" ::: "memory");                          \
    PH_MID; MFMA16Q(0, 0, aF, b0f); PH_END;                                     \
} while (0)

#define PH2S(BUFOFF, ...) do {                                                  \
    READ_B(b1f, BUFOFF, 1);                                                     \
    __VA_ARGS__;                                                                \
    PH_MID; MFMA16Q(0, 1, aF, b1f); PH_END;                                     \
} while (0)

#define PH3S(BUFOFF, ...) do {                                                  \
    READ_A(aF, BUFOFF, 1);                                                      \
    __VA_ARGS__;                                                                \
    PH_MID; MFMA16Q(1, 0, aF, b0f); PH_END;                                     \
} while (0)

#define PH4S(FN, ...) do {                                                      \
    __VA_ARGS__;                                                                \
    PH_MID; MFMA16Q(1, 1, aF, b1f);                                             \
    __builtin_amdgcn_s_setprio(0);                                              \
    asm volatile("s_waitcnt vmcnt(" #FN ")" ::: "memory");                      \
    __builtin_amdgcn_s_barrier();                                               \
    asm volatile("" ::: "memory");                                              \
} while (0)

#define PH4SNF(...) do {                                                        \
    __VA_ARGS__;                                                                \
    PH_MID; MFMA16Q(1, 1, aF, b1f); PH_END;                                     \
} while (0)

template <int EPI>
__global__ __launch_bounds__(512, 2) void gemm256_db(const ushort* __restrict__ A,
                                                     const ushort* __restrict__ B,
                                                     void* __restrict__ C,
                                                     const float* __restrict__ extra) {
    __shared__ ushort sA[2][256 * 64];
    __shared__ ushort sB[2][256 * 64];
    GEOM_COMMON(A, B);
    const char* sAc = (const char*)&sA[0][0];
    const char* sBc = (const char*)&sB[0][0];

    f32x4 acc[8][4];
#pragma unroll
    for (int i = 0; i < 8; ++i)
#pragma unroll
        for (int j = 0; j < 4; ++j) acc[i][j] = (f32x4){0.f, 0.f, 0.f, 0.f};
    short8 aF[2][4], b0f[2][2], b1f[2][2];

    STAGE2(gAl, sA[0], 0, CH_AE); STAGE2(gBl, sB[0], 0, CH_BE);
    STAGE2(gBl, sB[0], 0, CH_BL); STAGE2(gAl, sA[0], 0, CH_AL);
    STAGE2(gAl, sA[1], 64, CH_AE); STAGE2(gBl, sB[1], 64, CH_BE);
    STAGE2(gBl, sB[1], 64, CH_BL);
    asm volatile("s_waitcnt vmcnt(6)" ::: "memory");
    __builtin_amdgcn_s_barrier();
    asm volatile("" ::: "memory");

    for (int pr = 0; pr < 31; ++pr) {
        const int t = 2 * pr;
        const int kb1 = (t + 1) * 64, kb2 = (t + 2) * 64, kb3 = (t + 3) * 64;
        PH1S(0, STAGE2(gAl, sA[1], kb1, CH_AL));
        PH2S(0, STAGE2(gAl, sA[0], kb2, CH_AE));
        PH3S(0, STAGE2(gBl, sB[0], kb2, CH_BE));
        PH4S(6, STAGE2(gBl, sB[0], kb2, CH_BL));
        PH1S(32768, STAGE2(gAl, sA[0], kb2, CH_AL));
        PH2S(32768, STAGE2(gAl, sA[1], kb3, CH_AE));
        PH3S(32768, STAGE2(gBl, sB[1], kb3, CH_BE));
        PH4S(6, STAGE2(gBl, sB[1], kb3, CH_BL));
    }
    {
        PH1S(0, STAGE2(gAl, sA[1], 63 * 64, CH_AL));
        PH2S(0, ((void)0));
        PH3S(0, ((void)0));
        PH4S(0, ((void)0));
        PH1S(32768, ((void)0));
        PH2S(32768, ((void)0));
        PH3S(32768, ((void)0));
        PH4SNF(((void)0));
    }
    EPILOGUE_COMMON
}

// ---------- kernel 2: single-buffered, 64 KiB LDS, 2 blocks/CU (TLP) ------
// Per K-tile: read ALL 24 frags -> lgkm(0) -> barrier -> stage t+1 into the
// SAME buffer (8 gload_lds; HBM flies under MFMA) -> 64 MFMA -> vm(0) ->
// barrier. Within-block serial, but the co-resident block runs phase-shifted
// and fills the other pipe (m114 TLP). Hazards: lgkm(0)+barrier before any
// overwrite; vm(0)+barrier before any read of staged data. Registers: 96
// operand + 128 acc + ~25 addr = ~250 <= 512/wave at 4 waves/SIMD.
template <int EPI>
__global__ __launch_bounds__(512, 4) void gemm256_sb(const ushort* __restrict__ A,
                                                     const ushort* __restrict__ B,
                                                     void* __restrict__ C,
                                                     const float* __restrict__ extra) {
    __shared__ ushort sA[256 * 64];    // 32 KiB
    __shared__ ushort sB[256 * 64];    // 32 KiB
    GEOM_COMMON(A, B);
    const char* sAc = (const char*)&sA[0];
    const char* sBc = (const char*)&sB[0];

    f32x4 acc[8][4];
#pragma unroll
    for (int i = 0; i < 8; ++i)
#pragma unroll
        for (int j = 0; j < 4; ++j) acc[i][j] = (f32x4){0.f, 0.f, 0.f, 0.f};
    short8 a0[2][4], a1[2][4], b0[2][2], b1[2][2];   // 96 VGPR

    // prologue: stage tile 0 entirely
    STAGE2(gAl, sA, 0, CH_AE); STAGE2(gAl, sA, 0, CH_AL);
    STAGE2(gBl, sB, 0, CH_BE); STAGE2(gBl, sB, 0, CH_BL);
    asm volatile("s_waitcnt vmcnt(0)" ::: "memory");
    __builtin_amdgcn_s_barrier();
    asm volatile("" ::: "memory");

    for (int t = 0; t < 64; ++t) {
        // read all fragments of tile t into registers
        READ_A(a0, 0, 0); READ_A(a1, 0, 1);
        READ_B(b0, 0, 0); READ_B(b1, 0, 1);
        asm volatile("s_waitcnt lgkmcnt(0)" ::: "memory");
        __builtin_amdgcn_sched_barrier(0);
        BARX;                                   // all waves hold their regs
        if (t < 63) {                           // stage t+1 over tile t
            const int kb = (t + 1) * 64;
            STAGE2(gAl, sA, kb, CH_AE); STAGE2(gAl, sA, kb, CH_AL);
            STAGE2(gBl, sB, kb, CH_BE); STAGE2(gBl, sB, kb, CH_BL);
        }
        __builtin_amdgcn_s_setprio(1);
        MFMA16Q(0, 0, a0, b0); MFMA16Q(0, 1, a0, b1);
        MFMA16Q(1, 0, a1, b0); MFMA16Q(1, 1, a1, b1);
        __builtin_amdgcn_s_setprio(0);
        if (t < 63) asm volatile("s_waitcnt vmcnt(0)" ::: "memory");
        BARX;                                   // staged tile resident
    }
    EPILOGUE_COMMON
}

// ---------- launch ----------
extern "C" void kernel_launch(void* const* d_in, const int* in_sizes, int n_in,
                              void* d_out, int out_size, void* d_ws, size_t ws_size,
                              hipStream_t stream) {
    const float* x     = (const float*)d_in[0];   // (4,2048,4096) f32
    const int*   widx  = (const int*)  d_in[1];   // (4096,4096) i32
    const float* wscal = (const float*)d_in[2];   // (4096,)
    const float* bias  = (const float*)d_in[3];   // (4096,)
    const float* rot   = (const float*)d_in[4];   // (4096,4096) f32
    const float* cb    = (const float*)d_in[5];   // (16,)
    float* out = (float*)d_out;                   // (4,2048,4096) f32

    constexpr size_t IN_F = 4096, OUT_F = 4096, MTOK = 8192;
    char* ws = (char*)d_ws;
    ushort* wq   = (ushort*)(ws);                 // 32 MiB: codebook[idx] bf16
    ushort* rbuf = (ushort*)(ws + 33554432);      // 32 MiB: rotation bf16
    ushort* xb   = (ushort*)(ws + 67108864);      // 64 MiB: x bf16
    ushort* wb   = (ushort*)(ws + 134217728);     // 32 MiB: dequantized W bf16
    (void)ws_size; (void)in_sizes; (void)n_in; (void)out_size;

    // converts (memory-bound)
    {
        int n4 = (int)(OUT_F * IN_F / 4);
        k_idx2bf<<<n4 / 256, 256, 0, stream>>>(widx, cb, wq, n4);
        k_f2bf<<<n4 / 256, 256, 0, stream>>>(rot, rbuf, n4);
        int n4x = (int)(MTOK * IN_F / 4);
        k_f2bf<<<n4x / 256, 256, 0, stream>>>(x, xb, n4x);
    }

    // GEMM A (256 wgs = 1/CU): double-buffered kernel
    gemm256_db<0><<<dim3(256), 512, 0, stream>>>(wq, rbuf, (void*)wb, wscal);

    // GEMM B (512 wgs = 2/CU): single-buffered TLP kernel
    gemm256_sb<1><<<dim3(512), 512, 0, stream>>>(xb, wb, (void*)out, bias);
}

// Round 15
// 479.577 us; speedup vs baseline: 7.8252x; 7.8252x over previous
//
#include <hip/hip_runtime.h>

// ---------- types ----------
typedef short short8 __attribute__((ext_vector_type(8)));   // 8 bf16 as i16
typedef float f32x4 __attribute__((ext_vector_type(4)));

#define GLOBAL_AS __attribute__((address_space(1)))
#define LDS_AS    __attribute__((address_space(3)))

__device__ __forceinline__ unsigned short f2bf(float f) {
    unsigned u = __builtin_bit_cast(unsigned, f);
    u += 0x7fffu + ((u >> 16) & 1u);          // round-to-nearest-even
    return (unsigned short)(u >> 16);
}

// ---------- convert kernels (memory-bound, vectorized) ----------
__global__ __launch_bounds__(256) void k_idx2bf(const int* __restrict__ idx,
                                                const float* __restrict__ cb,
                                                ushort* __restrict__ out, int n4) {
    int i = blockIdx.x * 256 + threadIdx.x;
    if (i >= n4) return;
    int4 v = reinterpret_cast<const int4*>(idx)[i];
    ushort4 o;
    o.x = f2bf(cb[v.x]); o.y = f2bf(cb[v.y]);
    o.z = f2bf(cb[v.z]); o.w = f2bf(cb[v.w]);
    reinterpret_cast<ushort4*>(out)[i] = o;
}

__global__ __launch_bounds__(256) void k_f2bf(const float* __restrict__ in,
                                              ushort* __restrict__ out, int n4) {
    int i = blockIdx.x * 256 + threadIdx.x;
    if (i >= n4) return;
    float4 v = reinterpret_cast<const float4*>(in)[i];
    ushort4 o;
    o.x = f2bf(v.x); o.y = f2bf(v.y); o.z = f2bf(v.z); o.w = f2bf(v.w);
    reinterpret_cast<ushort4*>(out)[i] = o;
}

// ---------- 256x256 bf16 gemm_bt: unpinned waits + 8/4/8/4 reads ---------
// 512 thr = 8 waves (2M x 4N), per-wave 128x64, BK=64, 2 K-tile LDS dbuf.
// vs round 12 (best): (a) NO explicit lgkmcnt / sched_barrier pins — ds_reads
// are IR-visible, so the compiler emits fine-grained COUNTED lgkm waits and
// may interleave MFMAs with residual read service (the overlap my lgkm(0)+
// sched_barrier(0) pin was forbidding; rule-18 hoisting works FOR us here).
// (b) reads rebalanced 8/4/8/4: ph1 A0, ph2 B1, ph3 A1, ph4 B0(t+1) pre-read
// into dead b0f (matches m201's "4 or 8 ds_reads per phase"; zero reg cost).
// Hazard proof sketch (no explicit lgkm needed): every staged region's last
// ds_reads are consumed by an MFMA cluster BEFORE a barrier that precedes
// the stage -> MFMA issue requires operand drain -> reads drained before any
// wave reaches that barrier -> overwrite safe. Checked per region:
//   AL(t+1)@ph1 vs A1(t-1) reads (consumed ph3(t-1), 2 bars); AE(t+2)@ph2
//   vs A0(t) (consumed ph1, 1 bar); BE(t+2)@ph3 vs B0(t) (consumed ph1,
//   2 bars); BL(t+2)@ph4 vs B1(t) (consumed ph2, 2 bars).
// vm ledger (fences vm(6)@ph3end, vm(6)@ph4end): entering ph1(t) in-flight =
// {AE,BE,BL}(t+1); +AL(t+1),+AE(t+2),+BE(t+2) -> 12 -vm6-> {AL(t+1),AE(t+2),
// BE(t+2)} (BE(t+1) complete -> ph4's next-buf pre-read safe, fence precedes
// barrier); +BL(t+2) -> 8 -vm6-> {AE,BE,BL}(t+2). Steady invariant holds;
// prologue = 14 loads + vm(6) + pre-read B0(0); tails t62 vm(2)/vm(0), t63
// bare. Registers: 128 acc (AGPR) + 64 operands (aF/b0f/b1f) + ~20 addr.
// Swizzle (0 conflicts, r3/r6-verified): linear LDS dest + pre-swizzled
// global col (slot s of row r holds s^(r&7)) + XOR-folded read offsets.

#define CH_AE(j) ((((j) & 8) << 1) | ((j) & 7))
#define CH_AL(j) (CH_AE(j) + 8)
#define CH_BE(j) ((((j) & 12) << 1) | ((j) & 3))
#define CH_BL(j) (CH_BE(j) + 4)

#define STAGE2(GB, LW, KB, CF) do {                                             \
    const int c0_ = CF(2 * w);                                                  \
    const int c1_ = CF(2 * w + 1);                                              \
    __builtin_amdgcn_global_load_lds(                                           \
        (const GLOBAL_AS void*)((GB) + (size_t)c0_ * 32768 + (KB)),             \
        (LDS_AS void*)((LW) + c0_ * 512), 16, 0, 0);                            \
    __builtin_amdgcn_global_load_lds(                                           \
        (const GLOBAL_AS void*)((GB) + (size_t)c1_ * 32768 + (KB)),             \
        (LDS_AS void*)((LW) + c1_ * 512), 16, 0, 0);                            \
} while (0)

// static-offset fragment reads: BUF/MH/NH literal tokens -> ds imm
#define READ_A(DST, BUF, MH) do {                                               \
    _Pragma("unroll")                                                           \
    for (int mi = 0; mi < 4; ++mi)                                              \
        DST[0][mi] = *reinterpret_cast<const short8*>(                          \
            sAc + ak0 + ((BUF) + (MH) * 8192 + mi * 2048));                     \
    _Pragma("unroll")                                                           \
    for (int mi = 0; mi < 4; ++mi)                                              \
        DST[1][mi] = *reinterpret_cast<const short8*>(                          \
            sAc + ak1 + ((BUF) + (MH) * 8192 + mi * 2048));                     \
} while (0)

#define READ_B(DST, BUF, NH) do {                                               \
    _Pragma("unroll")                                                           \
    for (int ni = 0; ni < 2; ++ni)                                              \
        DST[0][ni] = *reinterpret_cast<const short8*>(                          \
            sBc + bk0 + ((BUF) + (NH) * 4096 + ni * 2048));                     \
    _Pragma("unroll")                                                           \
    for (int ni = 0; ni < 2; ++ni)                                              \
        DST[1][ni] = *reinterpret_cast<const short8*>(                          \
            sBc + bk1 + ((BUF) + (NH) * 4096 + ni * 2048));                     \
} while (0)

#define MFMA16Q(MH, NH, AF, BF)                                                 \
    _Pragma("unroll")                                                           \
    for (int k2 = 0; k2 < 2; ++k2)                                              \
        _Pragma("unroll")                                                       \
        for (int mi = 0; mi < 4; ++mi)                                          \
            _Pragma("unroll")                                                   \
            for (int ni = 0; ni < 2; ++ni)                                      \
                acc[(MH) * 4 + mi][(NH) * 2 + ni] =                             \
                    __builtin_amdgcn_mfma_f32_16x16x32_bf16(                    \
                        AF[k2][mi], BF[k2][ni], acc[(MH) * 4 + mi][(NH) * 2 + ni], 0, 0, 0)

// barrier with 2-way memory fence (pins loads/stages to their phase; MFMAs
// are register-only and may be scheduled freely by the compiler)
#define PH_BAR do {                                                             \
    asm volatile("" ::: "memory");                                              \
    __builtin_amdgcn_s_barrier();                                               \
    asm volatile("" ::: "memory");                                              \
} while (0)

// ph1: reads A0(8); stage; Q(0,0) = A0 x b0f (b0f pre-read last ph4)
#define PH1R(BUF, ...) do {                                                     \
    READ_A(aF, BUF, 0);                                                         \
    __VA_ARGS__;                                                                \
    PH_BAR;                                                                     \
    __builtin_amdgcn_s_setprio(1); MFMA16Q(0, 0, aF, b0f);                      \
    __builtin_amdgcn_s_setprio(0);                                              \
    PH_BAR;                                                                     \
} while (0)

// ph2: reads B1(4); stage; Q(0,1) = A0 x b1f
#define PH2R(BUF, ...) do {                                                     \
    READ_B(b1f, BUF, 1);                                                        \
    __VA_ARGS__;                                                                \
    PH_BAR;                                                                     \
    __builtin_amdgcn_s_setprio(1); MFMA16Q(0, 1, aF, b1f);                      \
    __builtin_amdgcn_s_setprio(0);                                              \
    PH_BAR;                                                                     \
} while (0)

// ph3: reads A1(8) into aF (A0 dead); stage; Q(1,0) = A1 x b0f; fence vm(FN)
#define PH3R(BUF, FN, ...) do {                                                 \
    READ_A(aF, BUF, 1);                                                         \
    __VA_ARGS__;                                                                \
    PH_BAR;                                                                     \
    __builtin_amdgcn_s_setprio(1); MFMA16Q(1, 0, aF, b0f);                      \
    __builtin_amdgcn_s_setprio(0);                                              \
    asm volatile("s_waitcnt vmcnt(" #FN ")" ::: "memory");                      \
    __builtin_amdgcn_s_barrier();                                               \
    asm volatile("" ::: "memory");                                              \
} while (0)

#define PH3RNF(BUF, ...) do {                                                   \
    READ_A(aF, BUF, 1);                                                         \
    __VA_ARGS__;                                                                \
    PH_BAR;                                                                     \
    __builtin_amdgcn_s_setprio(1); MFMA16Q(1, 0, aF, b0f);                      \
    __builtin_amdgcn_s_setprio(0);                                              \
    PH_BAR;                                                                     \
} while (0)

// ph4: pre-reads B0(t+1) from NEXT buffer into dead b0f; stage;
//      Q(1,1) = A1 x b1f; fence vm(FN)
#define PH4R(NBUF, FN, ...) do {                                                \
    READ_B(b0f, NBUF, 0);                                                       \
    __VA_ARGS__;                                                                \
    PH_BAR;                                                                     \
    __builtin_amdgcn_s_setprio(1); MFMA16Q(1, 1, aF, b1f);                      \
    __builtin_amdgcn_s_setprio(0);                                              \
    asm volatile("s_waitcnt vmcnt(" #FN ")" ::: "memory");                      \
    __builtin_amdgcn_s_barrier();                                               \
    asm volatile("" ::: "memory");                                              \
} while (0)

#define PH4RNF(...) do {                                                        \
    __VA_ARGS__;                                                                \
    PH_BAR;                                                                     \
    __builtin_amdgcn_s_setprio(1); MFMA16Q(1, 1, aF, b1f);                      \
    __builtin_amdgcn_s_setprio(0);                                              \
    PH_BAR;                                                                     \
} while (0)

// EPI=0: C=bf16, val = acc * extra[row]; EPI=1: C=f32, val = acc + extra[col]
template <int EPI>
__global__ __launch_bounds__(512, 2) void gemm256(const ushort* __restrict__ A,
                                                  const ushort* __restrict__ B,
                                                  void* __restrict__ C,
                                                  const float* __restrict__ extra) {
    constexpr int K = 4096, N = 4096;
    __shared__ ushort sA[2][256 * 64];
    __shared__ ushort sB[2][256 * 64];

    const int tid  = threadIdx.x;
    const int w    = tid >> 6;
    const int lane = tid & 63;
    const int wm = w >> 2, wn = w & 3;

    // XCD-aware swizzle (nwg % 8 == 0 for both grids)
    const int nwg = gridDim.x;
    const int sw  = ((int)blockIdx.x & 7) * (nwg >> 3) + ((int)blockIdx.x >> 3);
    const int m0 = (sw >> 4) * 256;      // 16 tiles per N-row (N=4096)
    const int n0 = (sw & 15) * 256;

    // staging bases: lane geometry folded once (global col pre-swizzled:
    // slot (lane&7) of row (lane>>3 mod 8) holds logical slot (lane&7)^(lane>>3))
    const int srow8 = lane >> 3;
    const int scol  = (((lane & 7) ^ (lane >> 3)) * 8);   // ushorts
    const ushort* gAl = A + (size_t)m0 * K + srow8 * 4096 + scol;
    const ushort* gBl = B + (size_t)n0 * K + srow8 * 4096 + scol;

    // fragment geometry (16x16x32: row=lane&15, k=(lane>>4)*8)
    const int fr   = lane & 15;
    const int fkb  = ((lane >> 4) & 3) * 16;          // byte offset along K
    const int swb  = (fr & 7) << 4;                   // read-side slot XOR
    const int arow = wm * 128 + fr;
    const int brow = wn * 64 + fr;
    // XOR-folded static read offsets (k2 folded pre-XOR; imms don't touch b4-6)
    const char* sAc = (const char*)&sA[0][0];
    const char* sBc = (const char*)&sB[0][0];
    const int ak0 = (arow * 128 + 0  + fkb) ^ swb;
    const int ak1 = (arow * 128 + 64 + fkb) ^ swb;
    const int bk0 = (brow * 128 + 0  + fkb) ^ swb;
    const int bk1 = (brow * 128 + 64 + fkb) ^ swb;

    f32x4 acc[8][4];
#pragma unroll
    for (int i = 0; i < 8; ++i)
#pragma unroll
        for (int j = 0; j < 4; ++j) acc[i][j] = (f32x4){0.f, 0.f, 0.f, 0.f};

    short8 aF[2][4], b0f[2][2], b1f[2][2];

    // ---- prologue: t0 (AE,BE,BL,AL) + t1 (AE,BE,BL) = 14 loads ----
    STAGE2(gAl, sA[0], 0, CH_AE); STAGE2(gBl, sB[0], 0, CH_BE);
    STAGE2(gBl, sB[0], 0, CH_BL); STAGE2(gAl, sA[0], 0, CH_AL);
    STAGE2(gAl, sA[1], 64, CH_AE); STAGE2(gBl, sB[1], 64, CH_BE);
    STAGE2(gBl, sB[1], 64, CH_BL);
    asm volatile("s_waitcnt vmcnt(6)" ::: "memory");   // tile0 fully resident
    __builtin_amdgcn_s_barrier();
    asm volatile("" ::: "memory");
    READ_B(b0f, 0, 0);                                 // pre-read B0(0)

    // ---- steady pairs: tiles 0..61 (stage refs <= tile 63) ----
    for (int pr = 0; pr < 31; ++pr) {
        const int t = 2 * pr;
        const int kb1 = (t + 1) * 64, kb2 = (t + 2) * 64, kb3 = (t + 3) * 64;
        // even tile t (buf0)
        PH1R(0,        STAGE2(gAl, sA[1], kb1, CH_AL));
        PH2R(0,        STAGE2(gAl, sA[0], kb2, CH_AE));
        PH3R(0, 6,     STAGE2(gBl, sB[0], kb2, CH_BE));
        PH4R(32768, 6, STAGE2(gBl, sB[0], kb2, CH_BL));
        // odd tile t+1 (buf1)
        PH1R(32768,    STAGE2(gAl, sA[0], kb2, CH_AL));
        PH2R(32768,    STAGE2(gAl, sA[1], kb3, CH_AE));
        PH3R(32768, 6, STAGE2(gBl, sB[1], kb3, CH_BE));
        PH4R(0, 6,     STAGE2(gBl, sB[1], kb3, CH_BL));
    }
    {   // ---- tail: tile 62 (buf0): stage only AL(63) ----
        PH1R(0,        STAGE2(gAl, sA[1], 63 * 64, CH_AL));
        PH2R(0,        ((void)0));
        PH3R(0, 2,     ((void)0));
        PH4R(32768, 0, ((void)0));
        // ---- tail: tile 63 (buf1): no stages, no fences, no pre-read ----
        PH1R(32768,    ((void)0));
        PH2R(32768,    ((void)0));
        PH3RNF(32768,  ((void)0));
        PH4RNF(((void)0));
    }

    // ---- epilogue: C/D layout col=lane&15, row=(lane>>4)*4+reg ----
    const int rb = m0 + wm * 128 + ((lane >> 4) * 4);
    const int cb = n0 + wn * 64 + (lane & 15);
    if (EPI == 0) {
        ushort* Cw = (ushort*)C;
#pragma unroll
        for (int mi = 0; mi < 8; ++mi) {
#pragma unroll
            for (int r = 0; r < 4; ++r) {
                const int row = rb + mi * 16 + r;
                const float s = extra[row];
#pragma unroll
                for (int ni = 0; ni < 4; ++ni)
                    Cw[(size_t)row * N + cb + ni * 16] = f2bf(acc[mi][ni][r] * s);
            }
        }
    } else {
        float* Cf = (float*)C;
#pragma unroll
        for (int ni = 0; ni < 4; ++ni) {
            const float b = extra[cb + ni * 16];
#pragma unroll
            for (int mi = 0; mi < 8; ++mi) {
#pragma unroll
                for (int r = 0; r < 4; ++r) {
                    const int row = rb + mi * 16 + r;
                    Cf[(size_t)row * N + cb + ni * 16] = acc[mi][ni][r] + b;
                }
            }
        }
    }
}

// ---------- launch ----------
extern "C" void kernel_launch(void* const* d_in, const int* in_sizes, int n_in,
                              void* d_out, int out_size, void* d_ws, size_t ws_size,
                              hipStream_t stream) {
    const float* x     = (const float*)d_in[0];   // (4,2048,4096) f32
    const int*   widx  = (const int*)  d_in[1];   // (4096,4096) i32
    const float* wscal = (const float*)d_in[2];   // (4096,)
    const float* bias  = (const float*)d_in[3];   // (4096,)
    const float* rot   = (const float*)d_in[4];   // (4096,4096) f32
    const float* cb    = (const float*)d_in[5];   // (16,)
    float* out = (float*)d_out;                   // (4,2048,4096) f32

    constexpr size_t IN_F = 4096, OUT_F = 4096, MTOK = 8192;
    char* ws = (char*)d_ws;
    ushort* wq   = (ushort*)(ws);                 // 32 MiB: codebook[idx] bf16
    ushort* rbuf = (ushort*)(ws + 33554432);      // 32 MiB: rotation bf16
    ushort* xb   = (ushort*)(ws + 67108864);      // 64 MiB: x bf16
    ushort* wb   = (ushort*)(ws + 134217728);     // 32 MiB: dequantized W bf16
    (void)ws_size; (void)in_sizes; (void)n_in; (void)out_size;

    // converts (memory-bound)
    {
        int n4 = (int)(OUT_F * IN_F / 4);
        k_idx2bf<<<n4 / 256, 256, 0, stream>>>(widx, cb, wq, n4);
        k_f2bf<<<n4 / 256, 256, 0, stream>>>(rot, rbuf, n4);
        int n4x = (int)(MTOK * IN_F / 4);
        k_f2bf<<<n4x / 256, 256, 0, stream>>>(x, xb, n4x);
    }

    // GEMM A: W[o,j] = scale[o] * sum_i Wq[o,i] R[j,i]   (M=4096 -> 256 wgs)
    gemm256<0><<<dim3(256), 512, 0, stream>>>(wq, rbuf, (void*)wb, wscal);

    // GEMM B: out[m,o] = sum_j x[m,j] W[o,j] + bias[o]   (M=8192 -> 512 wgs)
    gemm256<1><<<dim3(512), 512, 0, stream>>>(xb, wb, (void*)out, bias);
}